// Round 9
// baseline (18314.685 us; speedup 1.0000x reference)
//
#include <hip/hip_runtime.h>
#include <hip/hip_bf16.h>
#include <stdint.h>

#define BB   64
#define TT   2048
#define II   256
#define HH   256
#define G4   1024   // 4*H
#define NC   10

typedef _Float16 half2v __attribute__((ext_vector_type(2)));
typedef _Float16 half8v __attribute__((ext_vector_type(8)));
typedef float    float4v __attribute__((ext_vector_type(4)));

__device__ __forceinline__ float sigmf(float v) { return 1.f / (1.f + __expf(-v)); }
__device__ __forceinline__ float tanhf2(float v) { float e = __expf(2.f * v); return 1.f - 2.f / (e + 1.f); }

// Barrier WITHOUT vmcnt drain: keeps global loads in flight.
__device__ __forceinline__ void bar_lds() {
  asm volatile("s_waitcnt lgkmcnt(0)\n\ts_barrier" ::: "memory");
}

// ---------------------------------------------------------------------------
// K0a: WcT[g][i] = sum_j key[i][j] * W_ih[g][j]  (f16), biasc[g] = b_ih+b_hh
// ---------------------------------------------------------------------------
__global__ __launch_bounds__(1024) void prep_wc(
    const float* __restrict__ key, const float* __restrict__ Wih,
    const float* __restrict__ bih, const float* __restrict__ bhh,
    _Float16* __restrict__ WcT, float* __restrict__ biasc) {
  __shared__ float krow[II];
  const int i = blockIdx.x;
  const int g = threadIdx.x;
  if (g < II) krow[g] = key[(size_t)i * II + g];
  __syncthreads();
  const float4* w4 = (const float4*)(Wih + (size_t)g * II);
  float acc = 0.f;
#pragma unroll 8
  for (int j = 0; j < II / 4; ++j) {
    float4 w = w4[j];
    acc += w.x * krow[4 * j] + w.y * krow[4 * j + 1] + w.z * krow[4 * j + 2] + w.w * krow[4 * j + 3];
  }
  WcT[(size_t)g * II + i] = (_Float16)acc;
  if (i == 0) biasc[g] = bih[g] + bhh[g];
}

// ---------------------------------------------------------------------------
// K0c: pack W_hh into MFMA A-fragments over GATE-INTERLEAVED rows (content
// identical to the round-6-verified prep; storage order now [kt][w][m][lane]
// so a wave's 8 frags for one kt are 8 KB contiguous -> clean L2 streaming).
// Interleave: row' = 4k+q  (k = h-elem, q = gate 0..3 -> orig row q*256+k).
// Frag: lane holds 8 f16: row = (w*8+m)*16 + (lane&15), k = kt*32+(lane>>4)*8+jj.
// ---------------------------------------------------------------------------
__global__ __launch_bounds__(256) void prep_wfrag(
    const float* __restrict__ Whh, uint4* __restrict__ wrg) {
  const int id = blockIdx.x * 256 + threadIdx.x;   // 32768 = 8kt*8w*8m*64lane
  const int lane = id & 63;
  const int m  = (id >> 6) & 7;
  const int w  = (id >> 9) & 7;
  const int kt = id >> 12;                          // 0..7
  const int rowp = (w * 8 + m) * 16 + (lane & 15);  // interleaved row'
  const int g = (rowp & 3) * 256 + (rowp >> 2);     // original gate row
  const int k0 = kt * 32 + (lane >> 4) * 8;
  half8v frag;
#pragma unroll
  for (int jj = 0; jj < 8; ++jj) frag[jj] = (_Float16)Whh[(size_t)g * HH + k0 + jj];
  wrg[((kt * 8 + w) * 8 + m) * 64 + lane] = __builtin_bit_cast(uint4, frag);
}

// ---------------------------------------------------------------------------
// K1: packed x-projection GEMM (round-6-verified, unchanged).
//   uint2 index = (grp*TT + t)*4096 + ((w*8+m)*4+quad)*16 + l15
//   uint2 = ((xi,xf),(xg,xo)) for (b = grp*16+l15, t, ke = w*32+m*4+quad).
// ---------------------------------------------------------------------------
__global__ __launch_bounds__(256) void gemm_xproj(
    const float* __restrict__ x, const _Float16* __restrict__ WcT,
    const float* __restrict__ biasc, _Float16* __restrict__ xpk) {
  __shared__ __align__(16) _Float16 Asm[128][40];
  __shared__ __align__(16) _Float16 Bsm[128][40];
  const int t = threadIdx.x;
  const int n0 = blockIdx.x * 128;
  const int m0 = blockIdx.y * 128;
  const int r = t >> 1;
  const int hoff = (t & 1) * 16;
  const int lane = t & 63, wave = t >> 6;
  const int quad = lane >> 4, l15 = lane & 15;
  const int mh = (wave & 1) * 64, nh = (wave >> 1) * 64;
  float4v zero = {0.f, 0.f, 0.f, 0.f};
  float4v acc[4][4];
#pragma unroll
  for (int a = 0; a < 4; ++a)
#pragma unroll
    for (int b = 0; b < 4; ++b) acc[a][b] = zero;

  for (int kt = 0; kt < 8; ++kt) {
    const int k0 = kt * 32;
    const float4* xa = (const float4*)(x + (size_t)(m0 + r) * II + k0 + hoff);
    float4 f0 = xa[0], f1 = xa[1], f2 = xa[2], f3 = xa[3];
    half8v lo = {(_Float16)f0.x, (_Float16)f0.y, (_Float16)f0.z, (_Float16)f0.w,
                 (_Float16)f1.x, (_Float16)f1.y, (_Float16)f1.z, (_Float16)f1.w};
    half8v hi = {(_Float16)f2.x, (_Float16)f2.y, (_Float16)f2.z, (_Float16)f2.w,
                 (_Float16)f3.x, (_Float16)f3.y, (_Float16)f3.z, (_Float16)f3.w};
    const half8v* bsrc = (const half8v*)(WcT + (size_t)(n0 + r) * II + k0 + hoff);
    half8v b0 = bsrc[0], b1 = bsrc[1];
    *(half8v*)&Asm[r][hoff]     = lo;
    *(half8v*)&Asm[r][hoff + 8] = hi;
    *(half8v*)&Bsm[r][hoff]     = b0;
    *(half8v*)&Bsm[r][hoff + 8] = b1;
    __syncthreads();
    half8v af[4], bf[4];
#pragma unroll
    for (int mt = 0; mt < 4; ++mt) af[mt] = *(const half8v*)&Asm[mh + mt * 16 + l15][quad * 8];
#pragma unroll
    for (int nt = 0; nt < 4; ++nt) bf[nt] = *(const half8v*)&Bsm[nh + nt * 16 + l15][quad * 8];
#pragma unroll
    for (int mt = 0; mt < 4; ++mt)
#pragma unroll
      for (int nt = 0; nt < 4; ++nt)
        acc[mt][nt] = __builtin_amdgcn_mfma_f32_16x16x32_f16(af[mt], bf[nt], acc[mt][nt], 0, 0, 0);
    __syncthreads();
  }
  _Float16* dst = xpk;
#pragma unroll
  for (int nt = 0; nt < 4; ++nt) {
    const int col = n0 + nh + nt * 16 + l15;
    const float bias = biasc[col];
    const int ke = col & 255, q = col >> 8;
    const int slot = (((ke >> 5) * 8 + ((ke >> 2) & 7)) * 4) + (ke & 3);  // (w*8+m)*4+quad
#pragma unroll
    for (int mt = 0; mt < 4; ++mt) {
      const int mrow = m0 + mh + mt * 16 + quad * 4;
#pragma unroll
      for (int j = 0; j < 4; ++j) {
        const int rr = mrow + j;
        const int b = rr >> 11, tt = rr & 2047;
        dst[(((size_t)(b >> 4) * TT + tt) * 4096 + (size_t)slot * 16 + (b & 15)) * 4 + q] =
            (_Float16)(acc[mt][nt][j] + bias);
      }
    }
  }
}

// ---------------------------------------------------------------------------
// K2: sequential LSTM, 16 batches/WG (4 WGs), weights STREAMED from L2.
// Round 6's failure was the 46-fragment resident array (184 dwords) vs the
// allocator's fixed ~50/50 arch/AGPR split (128 arch at 2 waves/SIMD) ->
// permanent shuffle/spill (1745 VALU instrs/thread/step measured). This
// version holds ZERO resident weights: per kt, 8 fragments are loaded into a
// register double-buffer (fA/fB, 64 VGPRs) via coalesced global loads and
// consumed immediately by MFMA. W_hh (512 KB) is re-read every step but is
// L2-resident per XCD (4 WGs -> 4 XCDs, ~0.6 TB/s per XCD << 4.3 TB/s).
// Register budget: fA+fB 64 + x 16 + addr/misc ~20 arch, acc 32 AGPR ->
// fits the split with slack. The asm(""...) on voff blocks LICM from
// hoisting the t-invariant weight loads (the round-2 spill disaster mode).
// All layouts (frag mapping, hfr B-frag order, EPI gate math, xpk order)
// are byte-identical to the round-6 PASSING kernel.
// ---------------------------------------------------------------------------
__global__ __launch_bounds__(512, 2) void lstm_seq(
    const uint2* __restrict__ xpk, const uint4* __restrict__ wrg,
    float* __restrict__ hfin) {
  __shared__ __align__(16) _Float16 hfr[4096];         // 8 KB h, B-frag order
  const int t0 = threadIdx.x;
  const int w = t0 >> 6, lane = t0 & 63;
  const int l15 = lane & 15, quad = lane >> 4;
  const int bb = blockIdx.x * 16;

#pragma unroll
  for (int i = 0; i < 4; ++i) ((uint32_t*)hfr)[i * 512 + t0] = 0;  // h(-1)=0

  float c0 = 0.f, c1 = 0.f, c2 = 0.f, c3 = 0.f, c4 = 0.f, c5 = 0.f, c6 = 0.f, c7 = 0.f;
  const uint2* xg = xpk + (size_t)blockIdx.x * TT * 4096 + w * 512 + lane;
  const uint32_t voff0 = (uint32_t)((w * 512 + lane) * 16);  // byte offset of this thread's frag slot
  __syncthreads();

  const float4v zero = {0.f, 0.f, 0.f, 0.f};
  for (int t = 0; t < TT; ++t) {
    uint32_t voff = voff0;
    asm volatile("" : "+v"(voff));                   // opaque: blocks LICM of weight loads
    const uint4* wkt = (const uint4*)((const char*)wrg + voff);  // frag(kt,m) at [kt*4096 + m*64]
    const uint2* xt = xg + (size_t)t * 4096;

    uint4 fA[8], fB[8];
    float4v acc[8];
#define LOADG(buf, kt)                                                        \
    _Pragma("unroll")                                                         \
    for (int m = 0; m < 8; ++m) (buf)[m] = wkt[(kt) * 4096 + m * 64];
#define MFMA8(buf, kt)                                                        \
    {                                                                         \
      half8v hb = *(const half8v*)&hfr[(kt) * 512 + lane * 8];                \
      _Pragma("unroll")                                                       \
      for (int m = 0; m < 8; ++m)                                             \
        acc[m] = __builtin_amdgcn_mfma_f32_16x16x32_f16(                      \
            __builtin_bit_cast(half8v, (buf)[m]), hb, acc[m], 0, 0, 0);       \
    }
    LOADG(fA, 0)
    uint2 x0 = xt[0], x1 = xt[64], x2 = xt[128], x3 = xt[192];
    LOADG(fB, 1)
#pragma unroll
    for (int m = 0; m < 8; ++m) acc[m] = zero;
    MFMA8(fA, 0)
    LOADG(fA, 2)
    uint2 x4 = xt[256], x5 = xt[320];
    MFMA8(fB, 1)
    LOADG(fB, 3)
    MFMA8(fA, 2)
    LOADG(fA, 4)
    uint2 x6 = xt[384], x7 = xt[448];
    MFMA8(fB, 3)
    LOADG(fB, 5)
    MFMA8(fA, 4)
    LOADG(fA, 6)
    MFMA8(fB, 5)
    LOADG(fB, 7)
    MFMA8(fA, 6)
    MFMA8(fB, 7)
#undef LOADG
#undef MFMA8
    bar_lds();                                    // all B-frag reads done
#define EPI(m, xv, cs)                                                        \
    {                                                                         \
      half2v xa = __builtin_bit_cast(half2v, (xv).x);  /* (xi, xf) */         \
      half2v xb = __builtin_bit_cast(half2v, (xv).y);  /* (xg, xo) */         \
      float ig = sigmf(acc[m][0] + (float)xa.x);                              \
      float fg = sigmf(acc[m][1] + (float)xa.y);                              \
      float gg = tanhf2(acc[m][2] + (float)xb.x);                             \
      float og = sigmf(acc[m][3] + (float)xb.y);                              \
      cs = fg * cs + ig * gg;                                                 \
      float hh = og * tanhf2(cs);                                             \
      _Float16 hf = (_Float16)hh;                                             \
      uint32_t u = (uint32_t)__builtin_bit_cast(unsigned short, hf);          \
      uint32_t pA = u | (((uint32_t)__shfl_xor((int)u, 16, 64)) << 16);       \
      uint32_t pB = (uint32_t)__shfl_xor((int)pA, 32, 64);                    \
      if (quad == 0) {                                                        \
        uint2 pv; pv.x = pA; pv.y = pB;                                       \
        *(uint2*)&hfr[w * 512 + (((m) >> 1) * 16 + l15) * 8 + ((m) & 1) * 4] = pv; \
      }                                                                       \
      if (t == TT - 1) hfin[(size_t)(bb + l15) * HH + (w * 32 + (m) * 4 + quad)] = hh; \
    }
    EPI(0, x0, c0) EPI(1, x1, c1) EPI(2, x2, c2) EPI(3, x3, c3)
    EPI(4, x4, c4) EPI(5, x5, c5) EPI(6, x6, c6) EPI(7, x7, c7)
#undef EPI
    bar_lds();                                    // h(t) visible to all
  }
}

// ---------------------------------------------------------------------------
// K3: out[b][c] = h_last[b] . W_cls[c] + b_cls[c]
// ---------------------------------------------------------------------------
__global__ __launch_bounds__(256) void cls_k(
    const float* __restrict__ hfin, const float* __restrict__ Wcls,
    const float* __restrict__ bcls, float* __restrict__ out) {
  __shared__ float part[4][NC];
  const int b = blockIdx.x, tid = threadIdx.x;
  const int lane = tid & 63, wave = tid >> 6;
  float hv = hfin[(size_t)b * HH + tid];
#pragma unroll
  for (int c = 0; c < NC; ++c) {
    float p = hv * Wcls[c * HH + tid];
#pragma unroll
    for (int off = 32; off >= 1; off >>= 1) p += __shfl_down(p, off, 64);
    if (lane == 0) part[wave][c] = p;
  }
  __syncthreads();
  if (tid < NC) {
    out[(size_t)b * NC + tid] =
        part[0][tid] + part[1][tid] + part[2][tid] + part[3][tid] + bcls[tid];
  }
}

// ---------------------------------------------------------------------------
extern "C" void kernel_launch(void* const* d_in, const int* in_sizes, int n_in,
                              void* d_out, int out_size, void* d_ws, size_t ws_size,
                              hipStream_t stream) {
  (void)in_sizes; (void)n_in; (void)out_size; (void)ws_size;
  const float* x    = (const float*)d_in[0];
  const float* key  = (const float*)d_in[1];
  const float* Wih  = (const float*)d_in[2];
  const float* Whh  = (const float*)d_in[3];
  const float* bih  = (const float*)d_in[4];
  const float* bhh  = (const float*)d_in[5];
  const float* Wcls = (const float*)d_in[6];
  const float* bcls = (const float*)d_in[7];
  float* out = (float*)d_out;

  char* ws = (char*)d_ws;
  size_t off = 0;
  uint2* xpk     = (uint2*)(ws + off);    off += (size_t)BB * TT * 512 * 4;   // 268 MB
  uint4* wrg     = (uint4*)(ws + off);    off += (size_t)8 * 8 * 8 * 64 * 16; // 512 KB
  _Float16* WcT  = (_Float16*)(ws + off); off += (size_t)G4 * II * 2;
  float* biasc   = (float*)(ws + off);    off += (size_t)G4 * 4;
  float* hfin    = (float*)(ws + off);    off += (size_t)BB * HH * 4;

  hipLaunchKernelGGL(prep_wc,    dim3(II),  dim3(G4),  0, stream, key, Wih, bih, bhh, WcT, biasc);
  hipLaunchKernelGGL(prep_wfrag, dim3(128), dim3(256), 0, stream, Whh, wrg);
  hipLaunchKernelGGL(gemm_xproj, dim3(G4 / 128, (BB * TT) / 128), dim3(256), 0, stream,
                     x, WcT, biasc, (_Float16*)xpk);
  hipLaunchKernelGGL(lstm_seq, dim3(BB / 16), dim3(512), 0, stream, xpk, wrg, hfin);
  hipLaunchKernelGGL(cls_k,    dim3(BB), dim3(256), 0, stream, hfin, Wcls, bcls, out);
}